// Round 6
// baseline (301.189 us; speedup 1.0000x reference)
//
#include <hip/hip_runtime.h>

// B=2, S=2048, D=512, H=8, HS=64
#define NB 2
#define NS 2048
#define ND 512
#define NH 8
#define NHS 64

typedef __attribute__((ext_vector_type(4))) float f32x4;
typedef __attribute__((ext_vector_type(8))) short s16x8;

__device__ inline unsigned short f2bf(float f) {
  unsigned int u = __float_as_uint(f);
  unsigned int r = (u + 0x7FFFu + ((u >> 16) & 1u)) >> 16;  // RNE
  return (unsigned short)r;
}
// XOR swizzle for [rows][64] bf16 LDS tiles: elem ^= (row&7)<<3.
// b128 reads stay 16B-aligned; conflict-free for both row-slice and col-slice reads.
__device__ inline int swz(int row, int col) { return row * 64 + (col ^ ((row & 7) << 3)); }

// ---------------- K/V projection: C[m,n] = X[m,:] . W[n,:] + bias ----------------
// Grid: (8 n-tiles, 32 m-tiles), 256 threads (4 waves, 2x2 of 64x64).
// n-tile 0..3 -> K, 4..7 -> V (stored transposed per head: [bh][hs][s]).
// WS USE IS CAPPED AT 8 MB (K 4MB + V^T 4MB); Q is recomputed per-block in attn.
__global__ __launch_bounds__(256) void kv_kernel(
    const float* __restrict__ X, const float* __restrict__ wk, const float* __restrict__ wv,
    const float* __restrict__ bk, const float* __restrict__ bv,
    unsigned short* __restrict__ Kb, unsigned short* __restrict__ Vt) {
  __shared__ __align__(16) unsigned short As[128 * 64];
  __shared__ __align__(16) unsigned short Bs[128 * 64];
  const int tid = threadIdx.x;
  const int lane = tid & 63, wid = tid >> 6;
  const int lr = lane & 15, lh = lane >> 4;
  const int m0 = blockIdx.y * 128;
  const int nb = blockIdx.x;
  const int type = nb >> 2;          // 0=K 1=V
  const int wrow0 = (nb & 3) * 128;  // row within the selected W (= n within type)
  const float* W = (type == 0) ? wk : wv;
  const float* bias = (type == 0) ? bk : bv;
  const int wm = wid >> 1, wn = wid & 1;

  f32x4 acc[4][4] = {};

  for (int k0 = 0; k0 < 512; k0 += 64) {
    // stage 128x64 fp32 -> bf16 (reg-staged so we can swizzle + convert)
#pragma unroll
    for (int g = 0; g < 4; ++g) {
      int idx = tid + 256 * g;
      int row = idx >> 3, c8 = (idx & 7) * 8;
      const float* pa = X + (size_t)(m0 + row) * 512 + k0 + c8;
      const float* pb = W + (size_t)(wrow0 + row) * 512 + k0 + c8;
      f32x4 a0 = *(const f32x4*)pa, a1 = *(const f32x4*)(pa + 4);
      f32x4 b0 = *(const f32x4*)pb, b1 = *(const f32x4*)(pb + 4);
      s16x8 av, bv8;
#pragma unroll
      for (int j = 0; j < 4; ++j) {
        av[j] = (short)f2bf(a0[j]); av[4 + j] = (short)f2bf(a1[j]);
        bv8[j] = (short)f2bf(b0[j]); bv8[4 + j] = (short)f2bf(b1[j]);
      }
      *(s16x8*)&As[swz(row, c8)] = av;
      *(s16x8*)&Bs[swz(row, c8)] = bv8;
    }
    __syncthreads();
#pragma unroll
    for (int kk = 0; kk < 64; kk += 32) {
      s16x8 af[4], bf_[4];
#pragma unroll
      for (int f = 0; f < 4; ++f) {
        af[f] = *(const s16x8*)&As[swz(wm * 64 + f * 16 + lr, kk + lh * 8)];
        bf_[f] = *(const s16x8*)&Bs[swz(wn * 64 + f * 16 + lr, kk + lh * 8)];
      }
#pragma unroll
      for (int fm = 0; fm < 4; ++fm)
#pragma unroll
        for (int fn = 0; fn < 4; ++fn)
          acc[fm][fn] = __builtin_amdgcn_mfma_f32_16x16x32_bf16(af[fm], bf_[fn], acc[fm][fn], 0, 0, 0);
    }
    __syncthreads();
  }

  // epilogue: C mapping col=lane&15 (n), row=(lane>>4)*4+reg (m)
#pragma unroll
  for (int fn = 0; fn < 4; ++fn) {
    int n = wrow0 + wn * 64 + fn * 16 + lr;  // 0..511 within type
    int hh = n >> 6, hs = n & 63;
    float bb = bias[n];
#pragma unroll
    for (int fm = 0; fm < 4; ++fm) {
#pragma unroll
      for (int r = 0; r < 4; ++r) {
        int m = m0 + wm * 64 + fm * 16 + lh * 4 + r;
        int b = m >> 11, s = m & 2047;
        float val = acc[fm][fn][r] + bb;
        if (type == 0) {
          Kb[((size_t)(b * 8 + hh) * 2048 + s) * 64 + hs] = f2bf(val);
        } else {
          Vt[((size_t)(b * 8 + hh) * 64 + hs) * 2048 + s] = f2bf(val);
        }
      }
    }
  }
}

// ---------------- Flash attention with post-softmax w_X / mask ----------------
// Grid: (32 q-tiles, 8 heads, 2 batches), 256 threads = 4 waves; wave w owns q rows [w*16, w*16+16).
// Phase 0 recomputes the block's 64x64 Q tile (X . wq-head-slice, scaled 1/8) into LDS.
// out[b,q,h*64+hs] = mask[b,q] * sum_k( exp(s-m)*wX[b,q,k] * V[k,hs] ) / sum_k exp(s-m)
__global__ __launch_bounds__(256) void attn_kernel(
    const float* __restrict__ X, const float* __restrict__ wq, const float* __restrict__ bq,
    const unsigned short* __restrict__ Kb, const unsigned short* __restrict__ Vt,
    const float* __restrict__ wX, const float* __restrict__ mask, float* __restrict__ out) {
  __shared__ __align__(16) unsigned short Ks[64 * 64];
  __shared__ __align__(16) unsigned short Vs[64 * 64];  // holds V^T tile: [hs][key]
  __shared__ __align__(16) unsigned short Qs[64 * 64];
  __shared__ __align__(16) unsigned short Ps[4 * 16 * 64];  // per-wave P staging
  const int tid = threadIdx.x;
  const int lane = tid & 63, wid = tid >> 6;
  const int lr = lane & 15, lh = lane >> 4;
  const int qt = blockIdx.x, hh = blockIdx.y, b = blockIdx.z;
  const int bh = b * 8 + hh;
  const int q0 = qt * 64;

  // ---- Phase 0: Q tile = X[q0..q0+64) . wq[hh*64..+64)^T, into Qs (bf16, pre-scaled 1/8)
  // Reuse Ks (X-stage) and Vs (Wq-stage) as staging buffers.
  f32x4 qacc[4] = {};
  for (int k0 = 0; k0 < 512; k0 += 64) {
#pragma unroll
    for (int g = 0; g < 2; ++g) {
      int idx = tid + 256 * g;
      int row = idx >> 3, c8 = (idx & 7) * 8;
      const float* px = X + (size_t)(b * 2048 + q0 + row) * 512 + k0 + c8;
      const float* pw = wq + (size_t)(hh * 64 + row) * 512 + k0 + c8;
      f32x4 x0 = *(const f32x4*)px, x1 = *(const f32x4*)(px + 4);
      f32x4 w0 = *(const f32x4*)pw, w1 = *(const f32x4*)(pw + 4);
      s16x8 xv, wv8;
#pragma unroll
      for (int j = 0; j < 4; ++j) {
        xv[j] = (short)f2bf(x0[j]); xv[4 + j] = (short)f2bf(x1[j]);
        wv8[j] = (short)f2bf(w0[j]); wv8[4 + j] = (short)f2bf(w1[j]);
      }
      *(s16x8*)&Ks[swz(row, c8)] = xv;
      *(s16x8*)&Vs[swz(row, c8)] = wv8;
    }
    __syncthreads();
#pragma unroll
    for (int kk = 0; kk < 64; kk += 32) {
      s16x8 xa = *(const s16x8*)&Ks[swz(wid * 16 + lr, kk + lh * 8)];
#pragma unroll
      for (int fn = 0; fn < 4; ++fn) {
        s16x8 wf = *(const s16x8*)&Vs[swz(fn * 16 + lr, kk + lh * 8)];
        qacc[fn] = __builtin_amdgcn_mfma_f32_16x16x32_bf16(xa, wf, qacc[fn], 0, 0, 0);
      }
    }
    __syncthreads();
  }
  // write Q tile: C col=lr (head col), row=lh*4+r (q row within wave's 16)
#pragma unroll
  for (int fn = 0; fn < 4; ++fn) {
    int col = fn * 16 + lr;
    float bb = bq[hh * 64 + col];
#pragma unroll
    for (int r = 0; r < 4; ++r) {
      int row = wid * 16 + lh * 4 + r;
      Qs[swz(row, col)] = f2bf((qacc[fn][r] + bb) * 0.125f);
    }
  }
  __syncthreads();

  s16x8 qa[2];
#pragma unroll
  for (int c = 0; c < 2; ++c) qa[c] = *(const s16x8*)&Qs[swz(wid * 16 + lr, c * 32 + lh * 8)];

  float m_[4], l_[4];
  f32x4 o[4] = {};
#pragma unroll
  for (int r = 0; r < 4; ++r) { m_[r] = -__builtin_inff(); l_[r] = 0.f; }

  const int qrow_base = q0 + wid * 16 + lh * 4;  // + r
  const float* wxp = wX + ((size_t)b * 2048 + qrow_base) * 2048;  // + r*2048 + key

  for (int kt = 0; kt < 32; ++kt) {
    // stage K tile [key][hs] and V^T tile [hs][key]
#pragma unroll
    for (int g = 0; g < 2; ++g) {
      int idx = tid + 256 * g;
      int row = idx >> 3, c8 = (idx & 7) * 8;
      *(s16x8*)&Ks[swz(row, c8)] = *(const s16x8*)(Kb + ((size_t)bh * 2048 + kt * 64 + row) * 64 + c8);
      *(s16x8*)&Vs[swz(row, c8)] = *(const s16x8*)(Vt + ((size_t)bh * 64 + row) * 2048 + kt * 64 + c8);
    }
    __syncthreads();

    // S = Q K^T (Q pre-scaled): C rows = q, cols = key
    f32x4 sv[4] = {};
#pragma unroll
    for (int c = 0; c < 2; ++c) {
#pragma unroll
      for (int f = 0; f < 4; ++f) {
        s16x8 kf = *(const s16x8*)&Ks[swz(f * 16 + lr, c * 32 + lh * 8)];
        sv[f] = __builtin_amdgcn_mfma_f32_16x16x32_bf16(qa[c], kf, sv[f], 0, 0, 0);
      }
    }

    // online softmax: per q-row (4 rows per lane, replicated across 16-lane group)
    float tm[4];
#pragma unroll
    for (int r = 0; r < 4; ++r)
      tm[r] = fmaxf(fmaxf(sv[0][r], sv[1][r]), fmaxf(sv[2][r], sv[3][r]));
#pragma unroll
    for (int off = 1; off < 16; off <<= 1)
#pragma unroll
      for (int r = 0; r < 4; ++r) tm[r] = fmaxf(tm[r], __shfl_xor(tm[r], off));

    float sc[4];
#pragma unroll
    for (int r = 0; r < 4; ++r) {
      float nm = fmaxf(m_[r], tm[r]);
      sc[r] = __expf(m_[r] - nm);
      m_[r] = nm;
      l_[r] *= sc[r];
    }
#pragma unroll
    for (int f = 0; f < 4; ++f)
#pragma unroll
      for (int r = 0; r < 4; ++r) o[f][r] *= sc[r];

    float ls[4] = {0.f, 0.f, 0.f, 0.f};
#pragma unroll
    for (int f = 0; f < 4; ++f) {
      int key = kt * 64 + f * 16 + lr;
#pragma unroll
      for (int r = 0; r < 4; ++r) {
        float p = __expf(sv[f][r] - m_[r]);
        ls[r] += p;                              // denominator: exp only (pre-wX)
        float w = wxp[(size_t)r * 2048 + key];   // post-softmax edge weight
        Ps[wid * 1024 + swz(lh * 4 + r, f * 16 + lr)] = f2bf(p * w);
      }
    }
#pragma unroll
    for (int off = 1; off < 16; off <<= 1)
#pragma unroll
      for (int r = 0; r < 4; ++r) ls[r] += __shfl_xor(ls[r], off);
#pragma unroll
    for (int r = 0; r < 4; ++r) l_[r] += ls[r];

    // PV: A = P (16q x 64key), B = V^T-frag (hs x key) from Vs[hs][key]
#pragma unroll
    for (int c = 0; c < 2; ++c) {
      s16x8 pf = *(const s16x8*)&Ps[wid * 1024 + swz(lr, c * 32 + lh * 8)];
#pragma unroll
      for (int f = 0; f < 4; ++f) {
        s16x8 vf = *(const s16x8*)&Vs[swz(f * 16 + lr, c * 32 + lh * 8)];
        o[f] = __builtin_amdgcn_mfma_f32_16x16x32_bf16(pf, vf, o[f], 0, 0, 0);
      }
    }
    __syncthreads();  // before next tile overwrites Ks/Vs
  }

  // epilogue: out = mask * acc / l
#pragma unroll
  for (int r = 0; r < 4; ++r) {
    int q = qrow_base + r;
    float mk = mask[b * 2048 + q];
    float inv = mk / l_[r];
#pragma unroll
    for (int f = 0; f < 4; ++f) {
      out[((size_t)(b * 2048 + q)) * 512 + hh * 64 + f * 16 + lr] = o[f][r] * inv;
    }
  }
}

extern "C" void kernel_launch(void* const* d_in, const int* in_sizes, int n_in,
                              void* d_out, int out_size, void* d_ws, size_t ws_size,
                              hipStream_t stream) {
  const float* X = (const float*)d_in[0];
  const float* wX = (const float*)d_in[1];
  const float* mask = (const float*)d_in[2];
  const float* wq = (const float*)d_in[3];
  const float* bq = (const float*)d_in[4];
  const float* wk = (const float*)d_in[5];
  const float* bk = (const float*)d_in[6];
  const float* wv = (const float*)d_in[7];
  const float* bv = (const float*)d_in[8];
  float* out = (float*)d_out;

  // ws: Kb | Vt, each B*H*S*HS = 2,097,152 bf16 (4 MB) -> 8 MB total (== out size)
  unsigned short* Kb = (unsigned short*)d_ws;
  unsigned short* Vt = Kb + 2097152;

  kv_kernel<<<dim3(8, 32), 256, 0, stream>>>(X, wk, wv, bk, bv, Kb, Vt);
  attn_kernel<<<dim3(32, 8, 2), 256, 0, stream>>>(X, wq, bq, Kb, Vt, wX, mask, out);
}

// Round 9
// 185.424 us; speedup vs baseline: 1.6243x; 1.6243x over previous
//
#include <hip/hip_runtime.h>

// B=2, S=2048, D=512, H=8, HS=64
#define NB 2
#define NS 2048
#define ND 512
#define NH 8
#define NHS 64

typedef __attribute__((ext_vector_type(4))) float f32x4;
typedef __attribute__((ext_vector_type(8))) short s16x8;

__device__ inline unsigned short f2bf(float f) {
  unsigned int u = __float_as_uint(f);
  unsigned int r = (u + 0x7FFFu + ((u >> 16) & 1u)) >> 16;  // RNE
  return (unsigned short)r;
}
// XOR swizzle for [rows][64] bf16 LDS tiles: elem ^= (row&7)<<3.
__device__ inline int swz(int row, int col) { return row * 64 + (col ^ ((row & 7) << 3)); }

__device__ inline s16x8 pack8(const f32x4& a0, const f32x4& a1) {
  s16x8 v;
#pragma unroll
  for (int j = 0; j < 4; ++j) { v[j] = (short)f2bf(a0[j]); v[4 + j] = (short)f2bf(a1[j]); }
  return v;
}

// ---------------- K/V projection: C[m,n] = X[m,:] . W[n,:] + bias ----------------
// BM=64, BN=128: grid (8 n-tiles, 64 m-tiles) = 512 blocks (2/CU), 4 waves (2x2 of 32x64).
// n-tile 0..3 -> K, 4..7 -> V (stored transposed per head: [bh][hs][s]).
// Staging is reg-prefetched (write-late): loads for step k0+1 issue during step k0's MFMA.
__global__ __launch_bounds__(256) void kv_kernel(
    const float* __restrict__ X, const float* __restrict__ wk, const float* __restrict__ wv,
    const float* __restrict__ bk, const float* __restrict__ bv,
    unsigned short* __restrict__ Kb, unsigned short* __restrict__ Vt) {
  __shared__ __align__(16) unsigned short As[64 * 64];
  __shared__ __align__(16) unsigned short Bs[128 * 64];
  const int tid = threadIdx.x;
  const int lane = tid & 63, wid = tid >> 6;
  const int lr = lane & 15, lh = lane >> 4;
  const int m0 = blockIdx.y * 64;
  const int nb = blockIdx.x;
  const int type = nb >> 2;          // 0=K 1=V
  const int wrow0 = (nb & 3) * 128;  // row within the selected W (= n within type)
  const float* W = (type == 0) ? wk : wv;
  const float* bias = (type == 0) ? bk : bv;
  const int wm = wid >> 1, wn = wid & 1;

  f32x4 acc[2][4] = {};
  f32x4 ar[2][2], br[4][2];  // staged fp32 panels (write-late)

#define KV_LOAD(K0)                                                          \
  {                                                                          \
    _Pragma("unroll") for (int g = 0; g < 2; ++g) {                          \
      int idx = tid + 256 * g; int row = idx >> 3, c8 = (idx & 7) * 8;       \
      const float* pa = X + (size_t)(m0 + row) * 512 + (K0) + c8;            \
      ar[g][0] = *(const f32x4*)pa; ar[g][1] = *(const f32x4*)(pa + 4);      \
    }                                                                        \
    _Pragma("unroll") for (int g = 0; g < 4; ++g) {                          \
      int idx = tid + 256 * g; int row = idx >> 3, c8 = (idx & 7) * 8;       \
      const float* pb = W + (size_t)(wrow0 + row) * 512 + (K0) + c8;         \
      br[g][0] = *(const f32x4*)pb; br[g][1] = *(const f32x4*)(pb + 4);      \
    }                                                                        \
  }

  KV_LOAD(0);
  for (int k0 = 0; k0 < 512; k0 += 64) {
    // convert + write staged regs
#pragma unroll
    for (int g = 0; g < 2; ++g) {
      int idx = tid + 256 * g; int row = idx >> 3, c8 = (idx & 7) * 8;
      *(s16x8*)&As[swz(row, c8)] = pack8(ar[g][0], ar[g][1]);
    }
#pragma unroll
    for (int g = 0; g < 4; ++g) {
      int idx = tid + 256 * g; int row = idx >> 3, c8 = (idx & 7) * 8;
      *(s16x8*)&Bs[swz(row, c8)] = pack8(br[g][0], br[g][1]);
    }
    __syncthreads();
    if (k0 < 448) KV_LOAD(k0 + 64);  // prefetch next panel during MFMA
#pragma unroll
    for (int kk = 0; kk < 64; kk += 32) {
      s16x8 af[2], bf_[4];
#pragma unroll
      for (int f = 0; f < 2; ++f) af[f] = *(const s16x8*)&As[swz(wm * 32 + f * 16 + lr, kk + lh * 8)];
#pragma unroll
      for (int f = 0; f < 4; ++f) bf_[f] = *(const s16x8*)&Bs[swz(wn * 64 + f * 16 + lr, kk + lh * 8)];
#pragma unroll
      for (int fm = 0; fm < 2; ++fm)
#pragma unroll
        for (int fn = 0; fn < 4; ++fn)
          acc[fm][fn] = __builtin_amdgcn_mfma_f32_16x16x32_bf16(af[fm], bf_[fn], acc[fm][fn], 0, 0, 0);
    }
    __syncthreads();
  }
#undef KV_LOAD

  // epilogue: C mapping col=lane&15 (n), row=(lane>>4)*4+reg (m)
#pragma unroll
  for (int fn = 0; fn < 4; ++fn) {
    int n = wrow0 + wn * 64 + fn * 16 + lr;  // 0..511 within type
    int hh = n >> 6, hs = n & 63;
    float bb = bias[n];
#pragma unroll
    for (int fm = 0; fm < 2; ++fm) {
#pragma unroll
      for (int r = 0; r < 4; ++r) {
        int m = m0 + wm * 32 + fm * 16 + lh * 4 + r;
        int b = m >> 11, s = m & 2047;
        float val = acc[fm][fn][r] + bb;
        if (type == 0) {
          Kb[((size_t)(b * 8 + hh) * 2048 + s) * 64 + hs] = f2bf(val);
        } else {
          Vt[((size_t)(b * 8 + hh) * 64 + hs) * 2048 + s] = f2bf(val);
        }
      }
    }
  }
}

// ---------------- Flash attention with post-softmax w_X / mask ----------------
// Grid: (32 q-tiles, 8 heads, 2 batches), 4 waves; wave w owns q rows [w*16, w*16+16).
// Reg-prefetched staging (T14 write-late): K/V tile kt+1 and wX tile kt+1 load during tile kt.
__global__ __launch_bounds__(256) void attn_kernel(
    const float* __restrict__ X, const float* __restrict__ wq, const float* __restrict__ bq,
    const unsigned short* __restrict__ Kb, const unsigned short* __restrict__ Vt,
    const float* __restrict__ wX, const float* __restrict__ mask, float* __restrict__ out) {
  __shared__ __align__(16) unsigned short Ks[64 * 64];
  __shared__ __align__(16) unsigned short Vs[64 * 64];  // V^T tile: [hs][key]
  __shared__ __align__(16) unsigned short Qs[64 * 64];
  __shared__ __align__(16) unsigned short Ps[4 * 16 * 64];  // per-wave P staging
  const int tid = threadIdx.x;
  const int lane = tid & 63, wid = tid >> 6;
  const int lr = lane & 15, lh = lane >> 4;
  const int qt = blockIdx.x, hh = blockIdx.y, b = blockIdx.z;
  const int bh = b * 8 + hh;
  const int q0 = qt * 64;

  const int srow = tid >> 3, sc8 = (tid & 7) * 8;        // staging row/col for g=0
  const int srow1 = (tid + 256) >> 3;                    // staging row for g=1

  // ---- Phase 0: Q tile = X[q0..+64) . wq[hh*64..+64)^T -> Qs (bf16, pre-scaled 1/8)
  f32x4 qacc[4] = {};
  f32x4 xr[2][2], wr0[2][2];
#define Q_LOAD(K0)                                                           \
  {                                                                          \
    _Pragma("unroll") for (int g = 0; g < 2; ++g) {                          \
      int row = g ? srow1 : srow;                                            \
      const float* px = X + (size_t)(b * 2048 + q0 + row) * 512 + (K0) + sc8;\
      const float* pw = wq + (size_t)(hh * 64 + row) * 512 + (K0) + sc8;     \
      xr[g][0] = *(const f32x4*)px; xr[g][1] = *(const f32x4*)(px + 4);      \
      wr0[g][0] = *(const f32x4*)pw; wr0[g][1] = *(const f32x4*)(pw + 4);    \
    }                                                                        \
  }
  Q_LOAD(0);
  for (int k0 = 0; k0 < 512; k0 += 64) {
#pragma unroll
    for (int g = 0; g < 2; ++g) {
      int row = g ? srow1 : srow;
      *(s16x8*)&Ks[swz(row, sc8)] = pack8(xr[g][0], xr[g][1]);
      *(s16x8*)&Vs[swz(row, sc8)] = pack8(wr0[g][0], wr0[g][1]);
    }
    __syncthreads();
    if (k0 < 448) Q_LOAD(k0 + 64);
#pragma unroll
    for (int kk = 0; kk < 64; kk += 32) {
      s16x8 xa = *(const s16x8*)&Ks[swz(wid * 16 + lr, kk + lh * 8)];
#pragma unroll
      for (int fn = 0; fn < 4; ++fn) {
        s16x8 wf = *(const s16x8*)&Vs[swz(fn * 16 + lr, kk + lh * 8)];
        qacc[fn] = __builtin_amdgcn_mfma_f32_16x16x32_bf16(xa, wf, qacc[fn], 0, 0, 0);
      }
    }
    __syncthreads();
  }
#undef Q_LOAD

  const int qrow_base = q0 + wid * 16 + lh * 4;  // + r
  const float* wxp = wX + ((size_t)b * 2048 + qrow_base) * 2048;  // + r*2048 + key

  // issue main-loop tile-0 prefetches (cover under Qs write + barrier)
  s16x8 kreg[2], vreg[2];
  float wxf[4][4];
#define KV_TILE_LOAD(KT)                                                     \
  {                                                                          \
    _Pragma("unroll") for (int g = 0; g < 2; ++g) {                          \
      int row = g ? srow1 : srow;                                            \
      kreg[g] = *(const s16x8*)(Kb + ((size_t)bh * 2048 + (KT) * 64 + row) * 64 + sc8); \
      vreg[g] = *(const s16x8*)(Vt + ((size_t)bh * 64 + row) * 2048 + (KT) * 64 + sc8); \
    }                                                                        \
  }
#define WX_LOAD(KT)                                                          \
  {                                                                          \
    _Pragma("unroll") for (int f = 0; f < 4; ++f) {                          \
      int key = (KT) * 64 + f * 16 + lr;                                     \
      _Pragma("unroll") for (int r = 0; r < 4; ++r)                          \
        wxf[f][r] = wxp[(size_t)r * 2048 + key];                             \
    }                                                                        \
  }
  KV_TILE_LOAD(0);
  WX_LOAD(0);

  // write Q tile: C col=lr, row=lh*4+r
#pragma unroll
  for (int fn = 0; fn < 4; ++fn) {
    int col = fn * 16 + lr;
    float bb = bq[hh * 64 + col];
#pragma unroll
    for (int r = 0; r < 4; ++r) {
      int row = wid * 16 + lh * 4 + r;
      Qs[swz(row, col)] = f2bf((qacc[fn][r] + bb) * 0.125f);
    }
  }
  __syncthreads();

  s16x8 qa[2];
#pragma unroll
  for (int c = 0; c < 2; ++c) qa[c] = *(const s16x8*)&Qs[swz(wid * 16 + lr, c * 32 + lh * 8)];

  float m_[4], l_[4];
  f32x4 o[4] = {};
#pragma unroll
  for (int r = 0; r < 4; ++r) { m_[r] = -__builtin_inff(); l_[r] = 0.f; }

  for (int kt = 0; kt < 32; ++kt) {
    // write-late: staged K/V regs -> LDS
#pragma unroll
    for (int g = 0; g < 2; ++g) {
      int row = g ? srow1 : srow;
      *(s16x8*)&Ks[swz(row, sc8)] = kreg[g];
      *(s16x8*)&Vs[swz(row, sc8)] = vreg[g];
    }
    __syncthreads();
    if (kt + 1 < 32) KV_TILE_LOAD(kt + 1);  // prefetch next K/V tile

    // S = Q K^T (Q pre-scaled): C rows = q, cols = key
    f32x4 sv[4] = {};
#pragma unroll
    for (int c = 0; c < 2; ++c) {
#pragma unroll
      for (int f = 0; f < 4; ++f) {
        s16x8 kf = *(const s16x8*)&Ks[swz(f * 16 + lr, c * 32 + lh * 8)];
        sv[f] = __builtin_amdgcn_mfma_f32_16x16x32_bf16(qa[c], kf, sv[f], 0, 0, 0);
      }
    }

    // online softmax (4 q-rows per lane, replicated across 16-lane group)
    float tm[4];
#pragma unroll
    for (int r = 0; r < 4; ++r)
      tm[r] = fmaxf(fmaxf(sv[0][r], sv[1][r]), fmaxf(sv[2][r], sv[3][r]));
#pragma unroll
    for (int off = 1; off < 16; off <<= 1)
#pragma unroll
      for (int r = 0; r < 4; ++r) tm[r] = fmaxf(tm[r], __shfl_xor(tm[r], off));

    float sc[4];
#pragma unroll
    for (int r = 0; r < 4; ++r) {
      float nm = fmaxf(m_[r], tm[r]);
      sc[r] = __expf(m_[r] - nm);
      m_[r] = nm;
      l_[r] *= sc[r];
    }
#pragma unroll
    for (int f = 0; f < 4; ++f)
#pragma unroll
      for (int r = 0; r < 4; ++r) o[f][r] *= sc[r];

    float ls[4] = {0.f, 0.f, 0.f, 0.f};
#pragma unroll
    for (int f = 0; f < 4; ++f) {
#pragma unroll
      for (int r = 0; r < 4; ++r) {
        float p = __expf(sv[f][r] - m_[r]);
        ls[r] += p;                          // denominator: exp only (pre-wX)
        Ps[wid * 1024 + swz(lh * 4 + r, f * 16 + lr)] = f2bf(p * wxf[f][r]);
      }
    }
    if (kt + 1 < 32) WX_LOAD(kt + 1);  // prefetch next wX (WAR dep keeps it after use)
#pragma unroll
    for (int off = 1; off < 16; off <<= 1)
#pragma unroll
      for (int r = 0; r < 4; ++r) ls[r] += __shfl_xor(ls[r], off);
#pragma unroll
    for (int r = 0; r < 4; ++r) l_[r] += ls[r];

    // PV: A = P (16q x 64key), B from Vs[hs][key]
#pragma unroll
    for (int c = 0; c < 2; ++c) {
      s16x8 pf = *(const s16x8*)&Ps[wid * 1024 + swz(lr, c * 32 + lh * 8)];
#pragma unroll
      for (int f = 0; f < 4; ++f) {
        s16x8 vf = *(const s16x8*)&Vs[swz(f * 16 + lr, c * 32 + lh * 8)];
        o[f] = __builtin_amdgcn_mfma_f32_16x16x32_bf16(pf, vf, o[f], 0, 0, 0);
      }
    }
    __syncthreads();  // before next tile's ds_write
  }
#undef KV_TILE_LOAD
#undef WX_LOAD

  // epilogue: out = mask * acc / l
#pragma unroll
  for (int r = 0; r < 4; ++r) {
    int q = qrow_base + r;
    float mk = mask[b * 2048 + q];
    float inv = mk / l_[r];
#pragma unroll
    for (int f = 0; f < 4; ++f) {
      out[((size_t)(b * 2048 + q)) * 512 + hh * 64 + f * 16 + lr] = o[f][r] * inv;
    }
  }
}

extern "C" void kernel_launch(void* const* d_in, const int* in_sizes, int n_in,
                              void* d_out, int out_size, void* d_ws, size_t ws_size,
                              hipStream_t stream) {
  const float* X = (const float*)d_in[0];
  const float* wX = (const float*)d_in[1];
  const float* mask = (const float*)d_in[2];
  const float* wq = (const float*)d_in[3];
  const float* bq = (const float*)d_in[4];
  const float* wk = (const float*)d_in[5];
  const float* bk = (const float*)d_in[6];
  const float* wv = (const float*)d_in[7];
  const float* bv = (const float*)d_in[8];
  float* out = (float*)d_out;

  // ws: Kb | Vt, each B*H*S*HS = 2,097,152 bf16 (4 MB) -> 8 MB total (== out size)
  unsigned short* Kb = (unsigned short*)d_ws;
  unsigned short* Vt = Kb + 2097152;

  kv_kernel<<<dim3(8, 64), 256, 0, stream>>>(X, wk, wv, bk, bv, Kb, Vt);
  attn_kernel<<<dim3(32, 8, 2), 256, 0, stream>>>(X, wq, bq, Kb, Vt, wX, mask, out);
}

// Round 10
// 164.682 us; speedup vs baseline: 1.8289x; 1.1260x over previous
//
#include <hip/hip_runtime.h>

// B=2, S=2048, D=512, H=8, HS=64
typedef __attribute__((ext_vector_type(4))) float f32x4;
typedef __attribute__((ext_vector_type(8))) short s16x8;
typedef __attribute__((ext_vector_type(2))) unsigned int u32x2;

__device__ inline unsigned short f2bf(float f) {
  unsigned int u = __float_as_uint(f);
  unsigned int r = (u + 0x7FFFu + ((u >> 16) & 1u)) >> 16;  // RNE
  return (unsigned short)r;
}
// XOR swizzle for [rows][64] bf16 LDS tiles: elem ^= (row&7)<<3 (bits>=3 only:
// 4- and 8-elem aligned vector accesses stay contiguous).
__device__ inline int swz(int row, int col) { return row * 64 + (col ^ ((row & 7) << 3)); }

__device__ inline s16x8 pack8(const f32x4& a0, const f32x4& a1) {
  s16x8 v;
#pragma unroll
  for (int j = 0; j < 4; ++j) { v[j] = (short)f2bf(a0[j]); v[4 + j] = (short)f2bf(a1[j]); }
  return v;
}

// ---------------- K/V projection: C[m,n] = X[m,:] . W[n,:] + bias ----------------
// BM=64, BN=128, 512 threads = 8 waves (2 wm x 4 wn, each 32x32 = 2x2 frags).
// Grid (8 n-tiles, 64 m-tiles) = 512 blocks -> 2 blocks/CU x 8 waves = 50% occ.
// n-tile 0..3 -> K, 4..7 -> V (stored transposed per head: [bh][hs][s]).
__global__ __launch_bounds__(512) void kv_kernel(
    const float* __restrict__ X, const float* __restrict__ wk, const float* __restrict__ wv,
    const float* __restrict__ bk, const float* __restrict__ bv,
    unsigned short* __restrict__ Kb, unsigned short* __restrict__ Vt) {
  __shared__ __align__(16) unsigned short As[64 * 64];
  __shared__ __align__(16) unsigned short Bs[128 * 64];
  const int tid = threadIdx.x;
  const int lane = tid & 63, wid = tid >> 6;
  const int lr = lane & 15, lh = lane >> 4;
  const int m0 = blockIdx.y * 64;
  const int nb = blockIdx.x;
  const int type = nb >> 2;          // 0=K 1=V
  const int wrow0 = (nb & 3) * 128;  // row within the selected W (= n within type)
  const float* W = (type == 0) ? wk : wv;
  const float* bias = (type == 0) ? bk : bv;
  const int wm = wid >> 2, wn = wid & 3;

  f32x4 acc[2][2] = {};
  f32x4 ar[2], br[2][2];  // staged fp32 panels (write-late)

#define KV_LOAD(K0)                                                          \
  {                                                                          \
    { int row = tid >> 3, c8 = (tid & 7) * 8;                                \
      const float* pa = X + (size_t)(m0 + row) * 512 + (K0) + c8;            \
      ar[0] = *(const f32x4*)pa; ar[1] = *(const f32x4*)(pa + 4); }          \
    _Pragma("unroll") for (int g = 0; g < 2; ++g) {                          \
      int idx = tid + 512 * g; int row = idx >> 3, c8 = (idx & 7) * 8;       \
      const float* pb = W + (size_t)(wrow0 + row) * 512 + (K0) + c8;         \
      br[g][0] = *(const f32x4*)pb; br[g][1] = *(const f32x4*)(pb + 4);      \
    }                                                                        \
  }

  KV_LOAD(0);
  for (int k0 = 0; k0 < 512; k0 += 64) {
    {
      int row = tid >> 3, c8 = (tid & 7) * 8;
      *(s16x8*)&As[swz(row, c8)] = pack8(ar[0], ar[1]);
    }
#pragma unroll
    for (int g = 0; g < 2; ++g) {
      int idx = tid + 512 * g; int row = idx >> 3, c8 = (idx & 7) * 8;
      *(s16x8*)&Bs[swz(row, c8)] = pack8(br[g][0], br[g][1]);
    }
    __syncthreads();
    if (k0 < 448) KV_LOAD(k0 + 64);  // prefetch next panel during MFMA
#pragma unroll
    for (int kk = 0; kk < 64; kk += 32) {
      s16x8 af[2], bf_[2];
#pragma unroll
      for (int f = 0; f < 2; ++f) af[f] = *(const s16x8*)&As[swz(wm * 32 + f * 16 + lr, kk + lh * 8)];
#pragma unroll
      for (int f = 0; f < 2; ++f) bf_[f] = *(const s16x8*)&Bs[swz(wn * 32 + f * 16 + lr, kk + lh * 8)];
#pragma unroll
      for (int fm = 0; fm < 2; ++fm)
#pragma unroll
        for (int fn = 0; fn < 2; ++fn)
          acc[fm][fn] = __builtin_amdgcn_mfma_f32_16x16x32_bf16(af[fm], bf_[fn], acc[fm][fn], 0, 0, 0);
    }
    __syncthreads();
  }
#undef KV_LOAD

  // epilogue: C mapping col=lane&15 (n), row=(lane>>4)*4+reg (m)
#pragma unroll
  for (int fn = 0; fn < 2; ++fn) {
    int n = wrow0 + wn * 32 + fn * 16 + lr;  // 0..511 within type
    int hh = n >> 6, hs = n & 63;
    float bb = bias[n];
#pragma unroll
    for (int fm = 0; fm < 2; ++fm) {
#pragma unroll
      for (int r = 0; r < 4; ++r) {
        int m = m0 + wm * 32 + fm * 16 + lh * 4 + r;
        int b = m >> 11, s = m & 2047;
        float val = acc[fm][fn][r] + bb;
        if (type == 0) {
          Kb[((size_t)(b * 8 + hh) * 2048 + s) * 64 + hs] = f2bf(val);
        } else {
          Vt[((size_t)(b * 8 + hh) * 64 + hs) * 2048 + s] = f2bf(val);
        }
      }
    }
  }
}

// ---------------- Flash attention, swapped-QK^T in-register softmax ----------------
// Grid (32 q-tiles, 8 heads, 2 batches), 4 waves; wave w owns q rows [w*16, w*16+16).
// QK^T computed as mfma(K,Q) -> lane (lh,lr) holds S[q=lr][key=f*16+lh*4+r]:
// softmax row stats are scalar per lane (q=lr), reduced across the 4-lane lh group.
// P(*wX) packed in-register to bf16 pairs, 4x ds_write_b64 into Ps[q][key]; PV unchanged.
__global__ __launch_bounds__(256) void attn_kernel(
    const float* __restrict__ X, const float* __restrict__ wq, const float* __restrict__ bq,
    const unsigned short* __restrict__ Kb, const unsigned short* __restrict__ Vt,
    const float* __restrict__ wX, const float* __restrict__ mask, float* __restrict__ out) {
  __shared__ __align__(16) unsigned short Ks[64 * 64];
  __shared__ __align__(16) unsigned short Vs[64 * 64];  // V^T tile: [hs][key]
  __shared__ __align__(16) unsigned short Qs[64 * 64];
  __shared__ __align__(16) unsigned short Ps[4 * 16 * 64];  // per-wave P staging [q][key]
  const int tid = threadIdx.x;
  const int lane = tid & 63, wid = tid >> 6;
  const int lr = lane & 15, lh = lane >> 4;
  const int qt = blockIdx.x, hh = blockIdx.y, b = blockIdx.z;
  const int bh = b * 8 + hh;
  const int q0 = qt * 64;

  const int srow = tid >> 3, sc8 = (tid & 7) * 8;  // staging row/col for g=0
  const int srow1 = (tid + 256) >> 3;              // staging row for g=1

  // ---- Phase 0: Q tile = X[q0..+64) . wq[hh*64..+64)^T -> Qs (bf16, pre-scaled 1/8)
  f32x4 qacc[4] = {};
  f32x4 xr[2][2], wr0[2][2];
#define Q_LOAD(K0)                                                           \
  {                                                                          \
    _Pragma("unroll") for (int g = 0; g < 2; ++g) {                          \
      int row = g ? srow1 : srow;                                            \
      const float* px = X + (size_t)(b * 2048 + q0 + row) * 512 + (K0) + sc8;\
      const float* pw = wq + (size_t)(hh * 64 + row) * 512 + (K0) + sc8;     \
      xr[g][0] = *(const f32x4*)px; xr[g][1] = *(const f32x4*)(px + 4);      \
      wr0[g][0] = *(const f32x4*)pw; wr0[g][1] = *(const f32x4*)(pw + 4);    \
    }                                                                        \
  }
  Q_LOAD(0);
  for (int k0 = 0; k0 < 512; k0 += 64) {
#pragma unroll
    for (int g = 0; g < 2; ++g) {
      int row = g ? srow1 : srow;
      *(s16x8*)&Ks[swz(row, sc8)] = pack8(xr[g][0], xr[g][1]);
      *(s16x8*)&Vs[swz(row, sc8)] = pack8(wr0[g][0], wr0[g][1]);
    }
    __syncthreads();
    if (k0 < 448) Q_LOAD(k0 + 64);
#pragma unroll
    for (int kk = 0; kk < 64; kk += 32) {
      s16x8 xa = *(const s16x8*)&Ks[swz(wid * 16 + lr, kk + lh * 8)];
#pragma unroll
      for (int fn = 0; fn < 4; ++fn) {
        s16x8 wf = *(const s16x8*)&Vs[swz(fn * 16 + lr, kk + lh * 8)];
        qacc[fn] = __builtin_amdgcn_mfma_f32_16x16x32_bf16(xa, wf, qacc[fn], 0, 0, 0);
      }
    }
    __syncthreads();
  }
#undef Q_LOAD

  const int qrow_base = q0 + wid * 16 + lh * 4;              // o-layout q rows (+r)
  const int q_sm = q0 + wid * 16 + lr;                       // softmax-owned q row
  const float* wxq = wX + ((size_t)b * 2048 + q_sm) * 2048;  // + key

  // tile-0 prefetches (cover under Qs write + barrier)
  s16x8 kreg[2], vreg[2];
  f32x4 wxv[4];  // wxv[f][r] = wX[q_sm][kt*64 + f*16 + lh*4 + r]
#define KV_TILE_LOAD(KT)                                                     \
  {                                                                          \
    _Pragma("unroll") for (int g = 0; g < 2; ++g) {                          \
      int row = g ? srow1 : srow;                                            \
      kreg[g] = *(const s16x8*)(Kb + ((size_t)bh * 2048 + (KT) * 64 + row) * 64 + sc8); \
      vreg[g] = *(const s16x8*)(Vt + ((size_t)bh * 64 + row) * 2048 + (KT) * 64 + sc8); \
    }                                                                        \
  }
#define WX_LOAD(KT)                                                          \
  {                                                                          \
    _Pragma("unroll") for (int f = 0; f < 4; ++f)                            \
      wxv[f] = *(const f32x4*)(wxq + (KT) * 64 + f * 16 + lh * 4);           \
  }
  KV_TILE_LOAD(0);
  WX_LOAD(0);

  // write Q tile: C col=lr (head col), row=lh*4+r
#pragma unroll
  for (int fn = 0; fn < 4; ++fn) {
    int col = fn * 16 + lr;
    float bb = bq[hh * 64 + col];
#pragma unroll
    for (int r = 0; r < 4; ++r) {
      int row = wid * 16 + lh * 4 + r;
      Qs[swz(row, col)] = f2bf((qacc[fn][r] + bb) * 0.125f);
    }
  }
  __syncthreads();

  s16x8 qa[2];
#pragma unroll
  for (int c = 0; c < 2; ++c) qa[c] = *(const s16x8*)&Qs[swz(wid * 16 + lr, c * 32 + lh * 8)];

  float m_ = -__builtin_inff(), l_ = 0.f;  // scalar stats for q = q_sm
  f32x4 o[4] = {};

  for (int kt = 0; kt < 32; ++kt) {
    // write-late: staged K/V regs -> LDS
#pragma unroll
    for (int g = 0; g < 2; ++g) {
      int row = g ? srow1 : srow;
      *(s16x8*)&Ks[swz(row, sc8)] = kreg[g];
      *(s16x8*)&Vs[swz(row, sc8)] = vreg[g];
    }
    __syncthreads();
    if (kt + 1 < 32) KV_TILE_LOAD(kt + 1);  // prefetch next K/V tile

    // S^T = K Q^T (swapped): sv[f][r] = S[q=lr][key=f*16+lh*4+r]
    f32x4 sv[4] = {};
#pragma unroll
    for (int c = 0; c < 2; ++c) {
#pragma unroll
      for (int f = 0; f < 4; ++f) {
        s16x8 kf = *(const s16x8*)&Ks[swz(f * 16 + lr, c * 32 + lh * 8)];
        sv[f] = __builtin_amdgcn_mfma_f32_16x16x32_bf16(kf, qa[c], sv[f], 0, 0, 0);
      }
    }

    // in-lane 16-value max (tree), then 4-lane lh-group reduce
    float t0 = fmaxf(fmaxf(sv[0][0], sv[0][1]), fmaxf(sv[0][2], sv[0][3]));
    float t1 = fmaxf(fmaxf(sv[1][0], sv[1][1]), fmaxf(sv[1][2], sv[1][3]));
    float t2 = fmaxf(fmaxf(sv[2][0], sv[2][1]), fmaxf(sv[2][2], sv[2][3]));
    float t3 = fmaxf(fmaxf(sv[3][0], sv[3][1]), fmaxf(sv[3][2], sv[3][3]));
    float tm = fmaxf(fmaxf(t0, t1), fmaxf(t2, t3));
    tm = fmaxf(tm, __shfl_xor(tm, 16));
    tm = fmaxf(tm, __shfl_xor(tm, 32));

    float nm = fmaxf(m_, tm);
    float sc = __expf(m_ - nm);
    m_ = nm;
    l_ *= sc;
    // redistribute sc to o-layout rows (q = lh*4+r): source lane 16*lh + lh*4 + r
    float sc_o[4];
#pragma unroll
    for (int r = 0; r < 4; ++r) sc_o[r] = __shfl(sc, 20 * lh + r);
#pragma unroll
    for (int f = 0; f < 4; ++f)
#pragma unroll
      for (int r = 0; r < 4; ++r) o[f][r] *= sc_o[r];

    // P = exp(S-m), denominator accumulates exp only; numerator weight = P*wX
    float ls = 0.f;
#pragma unroll
    for (int f = 0; f < 4; ++f) {
      float pw[4];
#pragma unroll
      for (int r = 0; r < 4; ++r) {
        float p = __expf(sv[f][r] - m_);
        ls += p;
        pw[r] = p * wxv[f][r];
      }
      u32x2 pk;
      pk[0] = (unsigned int)f2bf(pw[0]) | ((unsigned int)f2bf(pw[1]) << 16);
      pk[1] = (unsigned int)f2bf(pw[2]) | ((unsigned int)f2bf(pw[3]) << 16);
      *(u32x2*)&Ps[wid * 1024 + swz(lr, f * 16 + lh * 4)] = pk;
    }
    if (kt + 1 < 32) WX_LOAD(kt + 1);  // prefetch next wX (WAR dep keeps it after use)
    ls += __shfl_xor(ls, 16);
    ls += __shfl_xor(ls, 32);
    l_ += ls;

    // PV: A = P[q][key] from Ps, B = V^T-frag from Vs[hs][key]
#pragma unroll
    for (int c = 0; c < 2; ++c) {
      s16x8 pf = *(const s16x8*)&Ps[wid * 1024 + swz(lr, c * 32 + lh * 8)];
#pragma unroll
      for (int f = 0; f < 4; ++f) {
        s16x8 vf = *(const s16x8*)&Vs[swz(f * 16 + lr, c * 32 + lh * 8)];
        o[f] = __builtin_amdgcn_mfma_f32_16x16x32_bf16(pf, vf, o[f], 0, 0, 0);
      }
    }
    __syncthreads();  // before next tile's ds_write
  }
#undef KV_TILE_LOAD
#undef WX_LOAD

  // epilogue: out = mask * acc / l  (l redistributed to o-layout rows)
  float l_o[4];
#pragma unroll
  for (int r = 0; r < 4; ++r) l_o[r] = __shfl(l_, 20 * lh + r);
#pragma unroll
  for (int r = 0; r < 4; ++r) {
    int q = qrow_base + r;
    float mk = mask[b * 2048 + q];
    float inv = mk / l_o[r];
#pragma unroll
    for (int f = 0; f < 4; ++f) {
      out[((size_t)(b * 2048 + q)) * 512 + hh * 64 + f * 16 + lr] = o[f][r] * inv;
    }
  }
}

extern "C" void kernel_launch(void* const* d_in, const int* in_sizes, int n_in,
                              void* d_out, int out_size, void* d_ws, size_t ws_size,
                              hipStream_t stream) {
  const float* X = (const float*)d_in[0];
  const float* wX = (const float*)d_in[1];
  const float* mask = (const float*)d_in[2];
  const float* wq = (const float*)d_in[3];
  const float* bq = (const float*)d_in[4];
  const float* wk = (const float*)d_in[5];
  const float* bk = (const float*)d_in[6];
  const float* wv = (const float*)d_in[7];
  const float* bv = (const float*)d_in[8];
  float* out = (float*)d_out;

  // ws: Kb | Vt, each B*H*S*HS = 2,097,152 bf16 (4 MB) -> 8 MB total (== out size)
  unsigned short* Kb = (unsigned short*)d_ws;
  unsigned short* Vt = Kb + 2097152;

  kv_kernel<<<dim3(8, 64), 512, 0, stream>>>(X, wk, wv, bk, bv, Kb, Vt);
  attn_kernel<<<dim3(32, 8, 2), 256, 0, stream>>>(X, wq, bq, Kb, Vt, wX, mask, out);
}